// Round 14
// baseline (209.203 us; speedup 1.0000x reference)
//
#include <hip/hip_runtime.h>
#include <hip/hip_fp16.h>
#include <math.h>

#define RESERVE 16384

__device__ __forceinline__ float2 cadd(float2 a, float2 b){ return make_float2(a.x+b.x, a.y+b.y); }
__device__ __forceinline__ float2 csub(float2 a, float2 b){ return make_float2(a.x-b.x, a.y-b.y); }
__device__ __forceinline__ float2 cmul(float2 a, float2 b){ return make_float2(a.x*b.x - a.y*b.y, a.x*b.y + a.y*b.x); }
__device__ __forceinline__ float2 cmulc(float2 a, float2 b){ // conj(a)*b
  return make_float2(a.x*b.x + a.y*b.y, a.x*b.y - a.y*b.x); }
__device__ __forceinline__ __half2 f2h(float2 v){ return __floats2half2_rn(v.x, v.y); }
__device__ __forceinline__ float2 h2f(__half2 h){ return __half22float2(h); }

#define SCHED_FENCE() __builtin_amdgcn_sched_barrier(0x7F)

__device__ __forceinline__ constexpr int rho4(int r) { return ((r & 3) << 2) | (r >> 2); }

template<int DIR> __device__ __forceinline__ float2 twc(float2 z, float c, float s) {
  const float si = (DIR < 0) ? s : -s;
  return make_float2(c*z.x - si*z.y, c*z.y + si*z.x);
}
template<int DIR> __device__ __forceinline__ float2 mulmi(float2 z) {
  return (DIR < 0) ? make_float2(z.y, -z.x) : make_float2(-z.y, z.x);
}

// FFT-16 on 16 register-resident values, constant twiddles (verified r4-r13).
template<int DIR, bool REV>
__device__ __forceinline__ void fft16(float2* v) {
  #define IX(i) (REV ? rho4(i) : (i))
  #pragma unroll
  for (int j0 = 0; j0 < 4; ++j0) {
    float2 a0 = v[IX(j0)], a1 = v[IX(j0+4)], a2 = v[IX(j0+8)], a3 = v[IX(j0+12)];
    float2 t0 = cadd(a0,a2), t1 = csub(a0,a2), t2 = cadd(a1,a3), d = csub(a1,a3);
    float2 t3 = (DIR < 0) ? make_float2(d.y,-d.x) : make_float2(-d.y,d.x);
    v[IX(j0)]    = cadd(t0,t2);
    v[IX(j0+4)]  = cadd(t1,t3);
    v[IX(j0+8)]  = csub(t0,t2);
    v[IX(j0+12)] = csub(t1,t3);
  }
  v[IX(5)]  = twc<DIR>(v[IX(5)],  0.92387953f, -0.38268343f);
  v[IX(6)]  = twc<DIR>(v[IX(6)],  0.70710678f, -0.70710678f);
  v[IX(7)]  = twc<DIR>(v[IX(7)],  0.38268343f, -0.92387953f);
  v[IX(9)]  = twc<DIR>(v[IX(9)],  0.70710678f, -0.70710678f);
  v[IX(10)] = mulmi<DIR>(v[IX(10)]);
  v[IX(11)] = twc<DIR>(v[IX(11)], -0.70710678f, -0.70710678f);
  v[IX(13)] = twc<DIR>(v[IX(13)],  0.38268343f, -0.92387953f);
  v[IX(14)] = twc<DIR>(v[IX(14)], -0.70710678f, -0.70710678f);
  v[IX(15)] = twc<DIR>(v[IX(15)], -0.92387953f,  0.38268343f);
  #pragma unroll
  for (int k1 = 0; k1 < 4; ++k1) {
    float2 a0 = v[IX(4*k1)], a1 = v[IX(4*k1+1)], a2 = v[IX(4*k1+2)], a3 = v[IX(4*k1+3)];
    float2 t0 = cadd(a0,a2), t1 = csub(a0,a2), t2 = cadd(a1,a3), d = csub(a1,a3);
    float2 t3 = (DIR < 0) ? make_float2(d.y,-d.x) : make_float2(-d.y,d.x);
    v[IX(4*k1)]   = cadd(t0,t2);
    v[IX(4*k1+1)] = cadd(t1,t3);
    v[IX(4*k1+2)] = csub(t0,t2);
    v[IX(4*k1+3)] = csub(t1,t3);
  }
  #undef IX
}

__device__ __forceinline__ void make_twf(int l, float2* twf) {
  float s, c;
  sincospif((float)l * (-1.0f/128.0f), &s, &c);
  const float2 w = make_float2(c, s);
  twf[0] = make_float2(1.f, 0.f);
  #pragma unroll
  for (int k = 1; k < 16; ++k) twf[k] = cmul(twf[k-1], w);
}

// 256-pt FFT per 16-lane group; trb stride-17 padded (verified r6-r13).
template<int DIR, bool REV1, bool HB>
__device__ __forceinline__ void fft256g(float2* v, void* trb, int l, const float2* twf) {
  fft16<DIR, REV1>(v);
  if (HB) {
    __half2* t = (__half2*)trb;
    #pragma unroll
    for (int r = 0; r < 16; ++r) {
      const int k1 = REV1 ? r : rho4(r);
      float2 z = v[r];
      z = (DIR < 0) ? cmul(twf[k1], z) : cmulc(twf[k1], z);
      t[k1 * 17 + l] = f2h(z);
    }
    SCHED_FENCE();
    #pragma unroll
    for (int j = 0; j < 16; ++j) v[j] = h2f(t[l * 17 + j]);
  } else {
    float2* t = (float2*)trb;
    #pragma unroll
    for (int r = 0; r < 16; ++r) {
      const int k1 = REV1 ? r : rho4(r);
      float2 z = v[r];
      z = (DIR < 0) ? cmul(twf[k1], z) : cmulc(twf[k1], z);
      t[k1 * 17 + l] = z;
    }
    SCHED_FENCE();
    #pragma unroll
    for (int j = 0; j < 16; ++j) v[j] = ((float2*)trb)[l * 17 + j];
  }
  SCHED_FENCE();
  fft16<DIR, false>(v);
}

#define GS32 276
#define GS16 280

// Swizzles (verified r7). SW: 256-wide tiles; SW16: 16-wide panel tiles.
__device__ __forceinline__ int SW(int row, int col) {
  return (row << 8) + (col ^ ((row & 7) << 2) ^ ((row & 1) << 4));
}
__device__ __forceinline__ int SW16(int r, int ul) {
  return (r << 4) + (ul ^ (r & 14));
}

// Panelized intermediate layout (half2 units, per image):
//   elem(u, r) at (u>>4)*4096 + r*16 + (u&15)

// ---------- Pass 1: row FFT (fp32 in) -> panelized Bt fp16 ----------
__global__ __launch_bounds__(256) void k_pass1(const float* __restrict__ x,
    __half2* __restrict__ Bt, int img0, int istep) {
  __shared__ __align__(16) char smraw[16384];      // rowstage f32 / outtile h2
  __shared__ __align__(16) float2 trbf[16 * GS32];
  float*   rowstage = (float*)smraw;
  __half2* outtile  = (__half2*)smraw;
  const int tid = threadIdx.x, g = tid >> 4, l = tid & 15;
  const int slot = blockIdx.y, img = img0 + slot * istep;
  const int r0 = blockIdx.x << 4;
  float2 twf[16]; make_twf(l, twf);
  const float* xsrc = x + ((size_t)img << 16) + (r0 << 8);
  #pragma unroll
  for (int it = 0; it < 4; ++it) {
    const int L = it * 1024 + tid * 4;
    const float4 d = *reinterpret_cast<const float4*>(xsrc + L);
    *reinterpret_cast<float4*>(rowstage + SW(L >> 8, L & 255)) = d;
  }
  __syncthreads();
  float2 v[16];
  #pragma unroll
  for (int j = 0; j < 16; ++j)
    v[j] = make_float2(rowstage[SW(g, l + (j << 4))], 0.f);
  __syncthreads();   // rowstage consumed; outtile (alias) writable
  fft256g<-1, false, false>(v, trbf + g * GS32, l, twf);
  #pragma unroll
  for (int rr = 0; rr < 16; ++rr)
    outtile[SW(g, l + (rho4(rr) << 4))] = f2h(v[rr]);
  __syncthreads();
  __half2* bdst = Bt + ((size_t)slot << 16) + (r0 << 4);
  #pragma unroll
  for (int it = 0; it < 4; ++it) {
    const int L = it * 1024 + tid * 4;
    const int p = L >> 8, rl = (L >> 4) & 15, ul0 = L & 15;
    const int4 d = *reinterpret_cast<const int4*>(outtile + SW(rl, (p << 4) + ul0));
    *reinterpret_cast<int4*>(bdst + (p << 12) + (L & 255)) = d;
  }
}

// ---- Pass 2: col FFT + mask + col IFFT; IN-PLACE on Bt panel p ----
// Each block reads exactly its own 16KB panel fully before writing it back;
// no cross-block sharing -> race-free. Footprint 134 MB (L3-resident).
// Fully-kept panels: col-IFFT(col-FFT(c)) = 256*c exactly -> scale-rewrite.
__global__ __launch_bounds__(256) void k_pass2(const __half2* __restrict__ Bt,
    __half2* __restrict__ Ct, const int* __restrict__ cutoffs, int img0, int istep) {
  __shared__ __align__(16) char smraw[16384];      // instage / outtile (h2)
  __shared__ __align__(16) __half2 trbh[16 * GS16];
  __half2* instage = (__half2*)smraw;
  __half2* outtile = (__half2*)smraw;
  const int tid = threadIdx.x, g = tid >> 4, l = tid & 15;
  const int slot = blockIdx.y, img = img0 + slot * istep;
  const int p = blockIdx.x;
  const int cut = cutoffs[img >> 6];   // 1..127
  const __half2* bsrc = Bt + ((size_t)slot << 16) + (p << 12);
  __half2* cdst = Ct + ((size_t)slot << 16) + (p << 12);
  const bool kept = (p * 16 >= cut) && (p * 16 + 15 < 256 - cut);
  if (kept) {
    const __half2 s = __floats2half2_rn(256.f, 256.f);
    #pragma unroll
    for (int it = 0; it < 4; ++it) {
      const int L = it * 1024 + tid * 4;
      int4 d = *reinterpret_cast<const int4*>(bsrc + L);
      __half2* h = reinterpret_cast<__half2*>(&d);
      h[0] = __hmul2(h[0], s); h[1] = __hmul2(h[1], s);
      h[2] = __hmul2(h[2], s); h[3] = __hmul2(h[3], s);
      *reinterpret_cast<int4*>(cdst + L) = d;
    }
    return;
  }
  float2 twf[16]; make_twf(l, twf);
  #pragma unroll
  for (int it = 0; it < 4; ++it) {
    const int L = it * 1024 + tid * 4;
    const int4 d = *reinterpret_cast<const int4*>(bsrc + L);
    const int r = L >> 4, ul0 = L & 15;
    const int i0 = SW16(r, ul0);
    *reinterpret_cast<int2*>(instage + i0) = make_int2(d.x, d.y);
    *reinterpret_cast<int2*>(instage + (i0 ^ 2)) = make_int2(d.z, d.w);
  }
  __syncthreads();
  __half2 hv[16];
  #pragma unroll
  for (int j = 0; j < 16; ++j) hv[j] = instage[SW16(l + (j << 4), g)];
  __syncthreads();   // instage consumed; outtile (alias) writable
  const int u = (p << 4) + g;
  float2 v[16];
  #pragma unroll
  for (int j = 0; j < 16; ++j) v[j] = h2f(hv[j]);
  fft256g<-1, false, true>(v, trbh + g * GS16, l, twf);
  if ((u < cut) | (u >= 256 - cut)) {
    #pragma unroll
    for (int rr = 0; rr < 16; ++rr) {
      const int vi = l + (rho4(rr) << 4);
      if (vi < cut || vi >= 256 - cut) v[rr] = make_float2(0.f, 0.f);
    }
  }
  fft256g<1, true, true>(v, trbh + g * GS16, l, twf);
  #pragma unroll
  for (int rr = 0; rr < 16; ++rr)
    outtile[SW16(l + (rho4(rr) << 4), g)] = f2h(v[rr]);
  __syncthreads();
  #pragma unroll
  for (int it = 0; it < 4; ++it) {
    const int L = it * 1024 + tid * 4;
    const int r = L >> 4, ul0 = L & 15;
    const int i0 = SW16(r, ul0);
    const int2 a = *reinterpret_cast<const int2*>(outtile + i0);
    const int2 b = *reinterpret_cast<const int2*>(outtile + (i0 ^ 2));
    *reinterpret_cast<int4*>(cdst + L) = make_int4(a.x, a.y, b.x, b.y);
  }
}

// ---------- Pass 3: row IFFT + |.| -> out (fp32), coalesced ----------
__global__ __launch_bounds__(256) void k_pass3(const __half2* __restrict__ Ct,
    float* __restrict__ out, int img0, int istep) {
  __shared__ __align__(16) char smraw[16384];      // instage h2 / outstage f32
  __shared__ __align__(16) __half2 trbh[16 * GS16];
  __half2* instage  = (__half2*)smraw;
  float*   outstage = (float*)smraw;
  const int tid = threadIdx.x, g = tid >> 4, l = tid & 15;
  const int slot = blockIdx.y, img = img0 + slot * istep;
  const int r0 = blockIdx.x << 4;
  float2 twf[16]; make_twf(l, twf);
  #pragma unroll
  for (int k = 0; k < 16; ++k) { twf[k].x *= 0.0625f; twf[k].y *= 0.0625f; }
  const __half2* csrc = Ct + ((size_t)slot << 16) + (r0 << 4);
  #pragma unroll
  for (int it = 0; it < 4; ++it) {
    const int L = it * 1024 + tid * 4;
    const int p = L >> 8, rl = (L >> 4) & 15, ul0 = L & 15;
    const int4 d = *reinterpret_cast<const int4*>(csrc + (p << 12) + (L & 255));
    *reinterpret_cast<int4*>(instage + SW(rl, (p << 4) + ul0)) = d;
  }
  __syncthreads();
  __half2 hv[16];
  #pragma unroll
  for (int j = 0; j < 16; ++j) hv[j] = instage[SW(g, l + (j << 4))];
  __syncthreads();   // instage consumed; outstage (alias) writable
  float2 v[16];
  #pragma unroll
  for (int j = 0; j < 16; ++j) v[j] = h2f(hv[j]);
  fft256g<1, false, true>(v, trbh + g * GS16, l, twf);
  #pragma unroll
  for (int rr = 0; rr < 16; ++rr) {
    const float2 z = v[rr];
    outstage[SW(g, l + (rho4(rr) << 4))] =
        __builtin_amdgcn_sqrtf(z.x*z.x + z.y*z.y) * (1.f/4096.f);
  }
  __syncthreads();
  float* odst = out + ((size_t)img << 16) + (r0 << 8);
  #pragma unroll
  for (int it = 0; it < 4; ++it) {
    const int L = it * 1024 + tid * 4;
    const float4 d = *reinterpret_cast<const float4*>(outstage + SW(L >> 8, L & 255));
    *reinterpret_cast<float4*>(odst + L) = d;
  }
}

// ------ Histogram: col FFT of panelized Bt (fp32 trb), ring bins ------
__global__ __launch_bounds__(256) void k_hist(const __half2* __restrict__ Bt,
    double* __restrict__ bins, int slot0, int sstep, int batch0) {
  __shared__ __align__(16) __half2 instage[4096];
  __shared__ __align__(16) float2 trbf[16 * GS32];
  __shared__ float whist[4][132];
  const int tid = threadIdx.x, g = tid >> 4, l = tid & 15, wave = tid >> 6;
  const int lb = blockIdx.y;
  const int batch = batch0 + lb;
  const size_t slot = (size_t)(slot0 + lb * sstep);
  const int p = blockIdx.x;
  const int u = (p << 4) + g;
  float2 twf[16]; make_twf(l, twf);
  for (int i = tid & 63; i < 132; i += 64) whist[wave][i] = 0.f;
  const __half2* bsrc = Bt + (slot << 16) + (p << 12);
  #pragma unroll
  for (int it = 0; it < 4; ++it) {
    const int L = it * 1024 + tid * 4;
    const int4 d = *reinterpret_cast<const int4*>(bsrc + L);
    const int r = L >> 4, ul0 = L & 15;
    const int i0 = SW16(r, ul0);
    *reinterpret_cast<int2*>(instage + i0) = make_int2(d.x, d.y);
    *reinterpret_cast<int2*>(instage + (i0 ^ 2)) = make_int2(d.z, d.w);
  }
  __syncthreads();
  float2 v[16];
  #pragma unroll
  for (int j = 0; j < 16; ++j) v[j] = h2f(instage[SW16(l + (j << 4), g)]);
  fft256g<-1, false, false>(v, trbf + g * GS32, l, twf);
  const int fc = (u < 128) ? u + 1 : 256 - u;
  #pragma unroll
  for (int rr = 0; rr < 16; ++rr) {
    const int vi = l + (rho4(rr) << 4);
    const int fu = (vi < 128) ? vi + 1 : 256 - vi;
    const int seg = fu > fc ? fu : fc;
    const float2 z = v[rr];
    atomicAdd(&whist[wave][seg], z.x*z.x + z.y*z.y);
  }
  __syncthreads();
  for (int s = tid; s < 129; s += 256) {
    const float sum = whist[0][s] + whist[1][s] + whist[2][s] + whist[3][s];
    if (sum != 0.f) atomicAdd(&bins[batch * 129 + s], (double)sum);
  }
}

__global__ void k_cutoff(const double* __restrict__ bins, int* __restrict__ cutoffs) {
  const int b = threadIdx.x;
  if (b < 8) {
    const double* Bv = bins + b * 129;
    double total = 0.0;
    for (int s = 0; s < 129; ++s) total += Bv[s];
    const double target = 0.4 * total;
    double cum = Bv[0];
    int cut = 5;
    bool found = false;
    for (int s = 1; s <= 127; ++s) {
      cum += Bv[s];
      if (!found && cum >= target) { cut = s; found = true; }
    }
    cutoffs[b] = cut;
  }
}

extern "C" void kernel_launch(void* const* d_in, const int* in_sizes, int n_in,
                              void* d_out, int out_size, void* d_ws, size_t ws_size,
                              hipStream_t stream) {
  const float* x = (const float*)d_in[0];
  float* out = (float*)d_out;
  char* wsb = (char*)d_ws;
  double* bins    = (double*)wsb;          // 8*129 doubles
  int*    cutoffs = (int*)(wsb + 8448);
  char*   payload = wsb + RESERVE;

  size_t avail = (ws_size > RESERVE) ? ws_size - (size_t)RESERVE : 0;
  // In-place pass2: only Bt needed, 256 KB per image -> 134 MB total,
  // fully L3-resident (256 MB Infinity Cache).
  long long Gl = (long long)(avail / 262144);
  int G = (Gl > 512) ? 512 : (int)Gl;
  if (G < 1) G = 1;
  __half2* Bt = (__half2*)payload;
  __half2* Ct = Bt;   // pass2 rewrites each panel in place (block-local)

  hipMemsetAsync(bins, 0, 8 * 129 * sizeof(double), stream);
  dim3 blk(256, 1, 1);

  if (G >= 512) {
    // Single full pass1, hist reads channel-0 slots of Bt (pre-mask).
    k_pass1<<<dim3(16, 512), blk, 0, stream>>>(x, Bt, 0, 1);
    k_hist <<<dim3(16, 8),   blk, 0, stream>>>(Bt, bins, 0, 64, 0);
    k_cutoff<<<dim3(1), dim3(64), 0, stream>>>(bins, cutoffs);
    k_pass2<<<dim3(16, 512), blk, 0, stream>>>(Bt, Ct, cutoffs, 0, 1);
    k_pass3<<<dim3(16, 512), blk, 0, stream>>>(Ct, out, 0, 1);
  } else {
    // Fallback: prepass on channel-0 images, then max-size chunks.
    int Gp = G > 8 ? 8 : G;
    for (int b0 = 0; b0 < 8; b0 += Gp) {
      int n = (8 - b0 < Gp) ? (8 - b0) : Gp;
      k_pass1<<<dim3(16, n), blk, 0, stream>>>(x, Bt, b0 * 64, 64);
      k_hist <<<dim3(16, n), blk, 0, stream>>>(Bt, bins, 0, 1, b0);
    }
    k_cutoff<<<dim3(1), dim3(64), 0, stream>>>(bins, cutoffs);
    for (int g0 = 0; g0 < 512; g0 += G) {
      int n = (512 - g0 < G) ? (512 - g0) : G;
      k_pass1<<<dim3(16, n), blk, 0, stream>>>(x, Bt, g0, 1);
      k_pass2<<<dim3(16, n), blk, 0, stream>>>(Bt, Ct, cutoffs, g0, 1);
      k_pass3<<<dim3(16, n), blk, 0, stream>>>(Ct, out, g0, 1);
    }
  }
}

// Round 15
// 206.432 us; speedup vs baseline: 1.0134x; 1.0134x over previous
//
#include <hip/hip_runtime.h>
#include <hip/hip_fp16.h>
#include <math.h>

#define RESERVE 16384

__device__ __forceinline__ float2 cadd(float2 a, float2 b){ return make_float2(a.x+b.x, a.y+b.y); }
__device__ __forceinline__ float2 csub(float2 a, float2 b){ return make_float2(a.x-b.x, a.y-b.y); }
__device__ __forceinline__ float2 cmul(float2 a, float2 b){ return make_float2(a.x*b.x - a.y*b.y, a.x*b.y + a.y*b.x); }
__device__ __forceinline__ float2 cmulc(float2 a, float2 b){ // conj(a)*b
  return make_float2(a.x*b.x + a.y*b.y, a.x*b.y - a.y*b.x); }
__device__ __forceinline__ __half2 f2h(float2 v){ return __floats2half2_rn(v.x, v.y); }
__device__ __forceinline__ float2 h2f(__half2 h){ return __half22float2(h); }

#define SCHED_FENCE() __builtin_amdgcn_sched_barrier(0x7F)

__device__ __forceinline__ constexpr int rho4(int r) { return ((r & 3) << 2) | (r >> 2); }

template<int DIR> __device__ __forceinline__ float2 twc(float2 z, float c, float s) {
  const float si = (DIR < 0) ? s : -s;
  return make_float2(c*z.x - si*z.y, c*z.y + si*z.x);
}
template<int DIR> __device__ __forceinline__ float2 mulmi(float2 z) {
  return (DIR < 0) ? make_float2(z.y, -z.x) : make_float2(-z.y, z.x);
}

// FFT-16 on 16 register-resident values, constant twiddles (verified r4-r14).
template<int DIR, bool REV>
__device__ __forceinline__ void fft16(float2* v) {
  #define IX(i) (REV ? rho4(i) : (i))
  #pragma unroll
  for (int j0 = 0; j0 < 4; ++j0) {
    float2 a0 = v[IX(j0)], a1 = v[IX(j0+4)], a2 = v[IX(j0+8)], a3 = v[IX(j0+12)];
    float2 t0 = cadd(a0,a2), t1 = csub(a0,a2), t2 = cadd(a1,a3), d = csub(a1,a3);
    float2 t3 = (DIR < 0) ? make_float2(d.y,-d.x) : make_float2(-d.y,d.x);
    v[IX(j0)]    = cadd(t0,t2);
    v[IX(j0+4)]  = cadd(t1,t3);
    v[IX(j0+8)]  = csub(t0,t2);
    v[IX(j0+12)] = csub(t1,t3);
  }
  v[IX(5)]  = twc<DIR>(v[IX(5)],  0.92387953f, -0.38268343f);
  v[IX(6)]  = twc<DIR>(v[IX(6)],  0.70710678f, -0.70710678f);
  v[IX(7)]  = twc<DIR>(v[IX(7)],  0.38268343f, -0.92387953f);
  v[IX(9)]  = twc<DIR>(v[IX(9)],  0.70710678f, -0.70710678f);
  v[IX(10)] = mulmi<DIR>(v[IX(10)]);
  v[IX(11)] = twc<DIR>(v[IX(11)], -0.70710678f, -0.70710678f);
  v[IX(13)] = twc<DIR>(v[IX(13)],  0.38268343f, -0.92387953f);
  v[IX(14)] = twc<DIR>(v[IX(14)], -0.70710678f, -0.70710678f);
  v[IX(15)] = twc<DIR>(v[IX(15)], -0.92387953f,  0.38268343f);
  #pragma unroll
  for (int k1 = 0; k1 < 4; ++k1) {
    float2 a0 = v[IX(4*k1)], a1 = v[IX(4*k1+1)], a2 = v[IX(4*k1+2)], a3 = v[IX(4*k1+3)];
    float2 t0 = cadd(a0,a2), t1 = csub(a0,a2), t2 = cadd(a1,a3), d = csub(a1,a3);
    float2 t3 = (DIR < 0) ? make_float2(d.y,-d.x) : make_float2(-d.y,d.x);
    v[IX(4*k1)]   = cadd(t0,t2);
    v[IX(4*k1+1)] = cadd(t1,t3);
    v[IX(4*k1+2)] = csub(t0,t2);
    v[IX(4*k1+3)] = csub(t1,t3);
  }
  #undef IX
}

__device__ __forceinline__ void make_twf(int l, float2* twf) {
  float s, c;
  sincospif((float)l * (-1.0f/128.0f), &s, &c);
  const float2 w = make_float2(c, s);
  twf[0] = make_float2(1.f, 0.f);
  #pragma unroll
  for (int k = 1; k < 16; ++k) twf[k] = cmul(twf[k-1], w);
}

// 256-pt FFT per 16-lane group; trb stride-17 padded (verified r6-r14).
template<int DIR, bool REV1, bool HB>
__device__ __forceinline__ void fft256g(float2* v, void* trb, int l, const float2* twf) {
  fft16<DIR, REV1>(v);
  if (HB) {
    __half2* t = (__half2*)trb;
    #pragma unroll
    for (int r = 0; r < 16; ++r) {
      const int k1 = REV1 ? r : rho4(r);
      float2 z = v[r];
      z = (DIR < 0) ? cmul(twf[k1], z) : cmulc(twf[k1], z);
      t[k1 * 17 + l] = f2h(z);
    }
    SCHED_FENCE();
    #pragma unroll
    for (int j = 0; j < 16; ++j) v[j] = h2f(t[l * 17 + j]);
  } else {
    float2* t = (float2*)trb;
    #pragma unroll
    for (int r = 0; r < 16; ++r) {
      const int k1 = REV1 ? r : rho4(r);
      float2 z = v[r];
      z = (DIR < 0) ? cmul(twf[k1], z) : cmulc(twf[k1], z);
      t[k1 * 17 + l] = z;
    }
    SCHED_FENCE();
    #pragma unroll
    for (int j = 0; j < 16; ++j) v[j] = ((float2*)trb)[l * 17 + j];
  }
  SCHED_FENCE();
  fft16<DIR, false>(v);
}

#define GS32 276
#define GS16 280

// Swizzles (verified r7). SW: 256-wide tiles; SW16: 16-wide panel tiles.
__device__ __forceinline__ int SW(int row, int col) {
  return (row << 8) + (col ^ ((row & 7) << 2) ^ ((row & 1) << 4));
}
__device__ __forceinline__ int SW16(int r, int ul) {
  return (r << 4) + (ul ^ (r & 14));
}

// Panelized intermediate layout (half2 units, per image):
//   elem(u, r) at (u>>4)*4096 + r*16 + (u&15)

// ---------- Pass 1: row FFT (fp32 in) -> panelized Bt fp16 ----------
// Single aliased LDS region (35328 B): rowstage -> trbf -> outtile.
// (Body verified correct in r10; combined here with r13's other passes.)
__global__ __launch_bounds__(256) void k_pass1(const float* __restrict__ x,
    __half2* __restrict__ Bt, int img0, int istep) {
  __shared__ __align__(16) char smraw[16 * GS32 * 8];   // 35328 B
  float*   rowstage = (float*)smraw;
  __half2* outtile  = (__half2*)smraw;
  float2*  trbf     = (float2*)smraw;
  const int tid = threadIdx.x, g = tid >> 4, l = tid & 15;
  const int slot = blockIdx.y, img = img0 + slot * istep;
  const int r0 = blockIdx.x << 4;
  float2 twf[16]; make_twf(l, twf);
  const float* xsrc = x + ((size_t)img << 16) + (r0 << 8);
  #pragma unroll
  for (int it = 0; it < 4; ++it) {
    const int L = it * 1024 + tid * 4;
    const float4 d = *reinterpret_cast<const float4*>(xsrc + L);
    *reinterpret_cast<float4*>(rowstage + SW(L >> 8, L & 255)) = d;
  }
  __syncthreads();
  float2 v[16];
  #pragma unroll
  for (int j = 0; j < 16; ++j)
    v[j] = make_float2(rowstage[SW(g, l + (j << 4))], 0.f);
  __syncthreads();   // rowstage consumed; trb (alias) writable
  fft256g<-1, false, false>(v, trbf + g * GS32, l, twf);
  __syncthreads();   // all trb reads done; outtile (alias) writable
  #pragma unroll
  for (int rr = 0; rr < 16; ++rr)
    outtile[SW(g, l + (rho4(rr) << 4))] = f2h(v[rr]);
  __syncthreads();
  __half2* bdst = Bt + ((size_t)slot << 16) + (r0 << 4);
  #pragma unroll
  for (int it = 0; it < 4; ++it) {
    const int L = it * 1024 + tid * 4;
    const int p = L >> 8, rl = (L >> 4) & 15, ul0 = L & 15;
    const int4 d = *reinterpret_cast<const int4*>(outtile + SW(rl, (p << 4) + ul0));
    *reinterpret_cast<int4*>(bdst + (p << 12) + (L & 255)) = d;
  }
}

// ---- Pass 2: col FFT + mask + col IFFT; Bt panel p -> Ct panel p ----
// Fully-kept panels: col-IFFT(col-FFT(c)) = 256*c exactly -> scale-copy.
__global__ __launch_bounds__(256) void k_pass2(const __half2* __restrict__ Bt,
    __half2* __restrict__ Ct, const int* __restrict__ cutoffs, int img0, int istep) {
  __shared__ __align__(16) char smraw[16384];      // instage / outtile (h2)
  __shared__ __align__(16) __half2 trbh[16 * GS16];
  __half2* instage = (__half2*)smraw;
  __half2* outtile = (__half2*)smraw;
  const int tid = threadIdx.x, g = tid >> 4, l = tid & 15;
  const int slot = blockIdx.y, img = img0 + slot * istep;
  const int p = blockIdx.x;
  const int cut = cutoffs[img >> 6];   // 1..127
  const __half2* bsrc = Bt + ((size_t)slot << 16) + (p << 12);
  __half2* cdst = Ct + ((size_t)slot << 16) + (p << 12);
  const bool kept = (p * 16 >= cut) && (p * 16 + 15 < 256 - cut);
  if (kept) {
    const __half2 s = __floats2half2_rn(256.f, 256.f);
    #pragma unroll
    for (int it = 0; it < 4; ++it) {
      const int L = it * 1024 + tid * 4;
      int4 d = *reinterpret_cast<const int4*>(bsrc + L);
      __half2* h = reinterpret_cast<__half2*>(&d);
      h[0] = __hmul2(h[0], s); h[1] = __hmul2(h[1], s);
      h[2] = __hmul2(h[2], s); h[3] = __hmul2(h[3], s);
      *reinterpret_cast<int4*>(cdst + L) = d;
    }
    return;
  }
  float2 twf[16]; make_twf(l, twf);
  #pragma unroll
  for (int it = 0; it < 4; ++it) {
    const int L = it * 1024 + tid * 4;
    const int4 d = *reinterpret_cast<const int4*>(bsrc + L);
    const int r = L >> 4, ul0 = L & 15;
    const int i0 = SW16(r, ul0);
    *reinterpret_cast<int2*>(instage + i0) = make_int2(d.x, d.y);
    *reinterpret_cast<int2*>(instage + (i0 ^ 2)) = make_int2(d.z, d.w);
  }
  __syncthreads();
  __half2 hv[16];
  #pragma unroll
  for (int j = 0; j < 16; ++j) hv[j] = instage[SW16(l + (j << 4), g)];
  __syncthreads();   // instage consumed; outtile (alias) writable
  const int u = (p << 4) + g;
  float2 v[16];
  #pragma unroll
  for (int j = 0; j < 16; ++j) v[j] = h2f(hv[j]);
  fft256g<-1, false, true>(v, trbh + g * GS16, l, twf);
  if ((u < cut) | (u >= 256 - cut)) {
    #pragma unroll
    for (int rr = 0; rr < 16; ++rr) {
      const int vi = l + (rho4(rr) << 4);
      if (vi < cut || vi >= 256 - cut) v[rr] = make_float2(0.f, 0.f);
    }
  }
  fft256g<1, true, true>(v, trbh + g * GS16, l, twf);
  #pragma unroll
  for (int rr = 0; rr < 16; ++rr)
    outtile[SW16(l + (rho4(rr) << 4), g)] = f2h(v[rr]);
  __syncthreads();
  #pragma unroll
  for (int it = 0; it < 4; ++it) {
    const int L = it * 1024 + tid * 4;
    const int r = L >> 4, ul0 = L & 15;
    const int i0 = SW16(r, ul0);
    const int2 a = *reinterpret_cast<const int2*>(outtile + i0);
    const int2 b = *reinterpret_cast<const int2*>(outtile + (i0 ^ 2));
    *reinterpret_cast<int4*>(cdst + L) = make_int4(a.x, a.y, b.x, b.y);
  }
}

// ---------- Pass 3: row IFFT + |.| -> out (fp32), coalesced ----------
__global__ __launch_bounds__(256) void k_pass3(const __half2* __restrict__ Ct,
    float* __restrict__ out, int img0, int istep) {
  __shared__ __align__(16) char smraw[16384];      // instage h2 / outstage f32
  __shared__ __align__(16) __half2 trbh[16 * GS16];
  __half2* instage  = (__half2*)smraw;
  float*   outstage = (float*)smraw;
  const int tid = threadIdx.x, g = tid >> 4, l = tid & 15;
  const int slot = blockIdx.y, img = img0 + slot * istep;
  const int r0 = blockIdx.x << 4;
  float2 twf[16]; make_twf(l, twf);
  #pragma unroll
  for (int k = 0; k < 16; ++k) { twf[k].x *= 0.0625f; twf[k].y *= 0.0625f; }
  const __half2* csrc = Ct + ((size_t)slot << 16) + (r0 << 4);
  #pragma unroll
  for (int it = 0; it < 4; ++it) {
    const int L = it * 1024 + tid * 4;
    const int p = L >> 8, rl = (L >> 4) & 15, ul0 = L & 15;
    const int4 d = *reinterpret_cast<const int4*>(csrc + (p << 12) + (L & 255));
    *reinterpret_cast<int4*>(instage + SW(rl, (p << 4) + ul0)) = d;
  }
  __syncthreads();
  __half2 hv[16];
  #pragma unroll
  for (int j = 0; j < 16; ++j) hv[j] = instage[SW(g, l + (j << 4))];
  __syncthreads();   // instage consumed; outstage (alias) writable
  float2 v[16];
  #pragma unroll
  for (int j = 0; j < 16; ++j) v[j] = h2f(hv[j]);
  fft256g<1, false, true>(v, trbh + g * GS16, l, twf);
  #pragma unroll
  for (int rr = 0; rr < 16; ++rr) {
    const float2 z = v[rr];
    outstage[SW(g, l + (rho4(rr) << 4))] =
        __builtin_amdgcn_sqrtf(z.x*z.x + z.y*z.y) * (1.f/4096.f);
  }
  __syncthreads();
  float* odst = out + ((size_t)img << 16) + (r0 << 8);
  #pragma unroll
  for (int it = 0; it < 4; ++it) {
    const int L = it * 1024 + tid * 4;
    const float4 d = *reinterpret_cast<const float4*>(outstage + SW(L >> 8, L & 255));
    *reinterpret_cast<float4*>(odst + L) = d;
  }
}

// ------ Histogram: col FFT of panelized Bt (fp32 trb), ring bins ------
__global__ __launch_bounds__(256) void k_hist(const __half2* __restrict__ Bt,
    double* __restrict__ bins, int slot0, int sstep, int batch0) {
  __shared__ __align__(16) __half2 instage[4096];
  __shared__ __align__(16) float2 trbf[16 * GS32];
  __shared__ float whist[4][132];
  const int tid = threadIdx.x, g = tid >> 4, l = tid & 15, wave = tid >> 6;
  const int lb = blockIdx.y;
  const int batch = batch0 + lb;
  const size_t slot = (size_t)(slot0 + lb * sstep);
  const int p = blockIdx.x;
  const int u = (p << 4) + g;
  float2 twf[16]; make_twf(l, twf);
  for (int i = tid & 63; i < 132; i += 64) whist[wave][i] = 0.f;
  const __half2* bsrc = Bt + (slot << 16) + (p << 12);
  #pragma unroll
  for (int it = 0; it < 4; ++it) {
    const int L = it * 1024 + tid * 4;
    const int4 d = *reinterpret_cast<const int4*>(bsrc + L);
    const int r = L >> 4, ul0 = L & 15;
    const int i0 = SW16(r, ul0);
    *reinterpret_cast<int2*>(instage + i0) = make_int2(d.x, d.y);
    *reinterpret_cast<int2*>(instage + (i0 ^ 2)) = make_int2(d.z, d.w);
  }
  __syncthreads();
  float2 v[16];
  #pragma unroll
  for (int j = 0; j < 16; ++j) v[j] = h2f(instage[SW16(l + (j << 4), g)]);
  fft256g<-1, false, false>(v, trbf + g * GS32, l, twf);
  const int fc = (u < 128) ? u + 1 : 256 - u;
  #pragma unroll
  for (int rr = 0; rr < 16; ++rr) {
    const int vi = l + (rho4(rr) << 4);
    const int fu = (vi < 128) ? vi + 1 : 256 - vi;
    const int seg = fu > fc ? fu : fc;
    const float2 z = v[rr];
    atomicAdd(&whist[wave][seg], z.x*z.x + z.y*z.y);
  }
  __syncthreads();
  for (int s = tid; s < 129; s += 256) {
    const float sum = whist[0][s] + whist[1][s] + whist[2][s] + whist[3][s];
    if (sum != 0.f) atomicAdd(&bins[batch * 129 + s], (double)sum);
  }
}

__global__ void k_cutoff(const double* __restrict__ bins, int* __restrict__ cutoffs) {
  const int b = threadIdx.x;
  if (b < 8) {
    const double* Bv = bins + b * 129;
    double total = 0.0;
    for (int s = 0; s < 129; ++s) total += Bv[s];
    const double target = 0.4 * total;
    double cum = Bv[0];
    int cut = 5;
    bool found = false;
    for (int s = 1; s <= 127; ++s) {
      cum += Bv[s];
      if (!found && cum >= target) { cut = s; found = true; }
    }
    cutoffs[b] = cut;
  }
}

extern "C" void kernel_launch(void* const* d_in, const int* in_sizes, int n_in,
                              void* d_out, int out_size, void* d_ws, size_t ws_size,
                              hipStream_t stream) {
  const float* x = (const float*)d_in[0];
  float* out = (float*)d_out;
  char* wsb = (char*)d_ws;
  double* bins    = (double*)wsb;          // 8*129 doubles
  int*    cutoffs = (int*)(wsb + 8448);
  char*   payload = wsb + RESERVE;

  size_t avail = (ws_size > RESERVE) ? ws_size - (size_t)RESERVE : 0;
  long long Gl = (long long)(avail / 524288);   // Bt + Ct, 256 KB each per image
  int G = (Gl > 512) ? 512 : (int)Gl;
  if (G < 1) G = 1;
  __half2* Bt = (__half2*)payload;
  __half2* Ct = (__half2*)(payload + (size_t)G * 262144);

  hipMemsetAsync(bins, 0, 8 * 129 * sizeof(double), stream);
  dim3 blk(256, 1, 1);

  if (G >= 512) {
    // Single full pass1, hist reads channel-0 slots of the main Bt directly.
    k_pass1<<<dim3(16, 512), blk, 0, stream>>>(x, Bt, 0, 1);
    k_hist <<<dim3(16, 8),   blk, 0, stream>>>(Bt, bins, 0, 64, 0);
    k_cutoff<<<dim3(1), dim3(64), 0, stream>>>(bins, cutoffs);
    k_pass2<<<dim3(16, 512), blk, 0, stream>>>(Bt, Ct, cutoffs, 0, 1);
    k_pass3<<<dim3(16, 512), blk, 0, stream>>>(Ct, out, 0, 1);
  } else {
    // Fallback: prepass on channel-0 images, then max-size chunks.
    int Gp = G > 8 ? 8 : G;
    for (int b0 = 0; b0 < 8; b0 += Gp) {
      int n = (8 - b0 < Gp) ? (8 - b0) : Gp;
      k_pass1<<<dim3(16, n), blk, 0, stream>>>(x, Bt, b0 * 64, 64);
      k_hist <<<dim3(16, n), blk, 0, stream>>>(Bt, bins, 0, 1, b0);
    }
    k_cutoff<<<dim3(1), dim3(64), 0, stream>>>(bins, cutoffs);
    for (int g0 = 0; g0 < 512; g0 += G) {
      int n = (512 - g0 < G) ? (512 - g0) : G;
      k_pass1<<<dim3(16, n), blk, 0, stream>>>(x, Bt, g0, 1);
      k_pass2<<<dim3(16, n), blk, 0, stream>>>(Bt, Ct, cutoffs, g0, 1);
      k_pass3<<<dim3(16, n), blk, 0, stream>>>(Ct, out, g0, 1);
    }
  }
}